// Round 1
// 909.470 us; speedup vs baseline: 1.3341x; 1.3341x over previous
//
#include <hip/hip_runtime.h>
#include <stdint.h>

// ---- problem dims (BailingMoE: T=1024 H=2048 E=16 I=1408 S=2 topk=4) ----
// All tensors FLOAT32. fp32->bf16 RNE conversion during reg staging; MFMA is
// bf16 with fp32 accumulate. Routed experts computed SPARSELY (top-4 only).
// v2: 128x64 gateup tile (64 AGPR acc -> 2-3 waves/SIMD vs 1), reg prefetch
//     of next K-tile, LDS row pitch 40 (2-way max bank conflict), fused
//     routed+shared launches (z-extended grids), out pre-zeroed + atomics.
#define T_TOK 1024
#define H_DIM 2048
#define E_NUM 16
#define I_DIM 1408
#define IS_DIM 2816   // I*S (shared intermediate half-width)
#define TOPK 4

#define BK 32
#define LDP 40        // LDS row pitch in bf16 elems (80 B, 16B-aligned)

typedef unsigned short u16;
typedef __bf16 bf16x8 __attribute__((ext_vector_type(8)));
typedef float f32x4 __attribute__((ext_vector_type(4)));

__device__ __forceinline__ u16 f2bf(float f) {
  unsigned int v; __builtin_memcpy(&v, &f, 4);
  unsigned int lsb = (v >> 16) & 1u;
  v += 0x7fffu + lsb;   // RNE (finite values only)
  return (u16)(v >> 16);
}

__device__ __forceinline__ uint2 cvt4(float4 v) {
  uint2 o;
  o.x = (unsigned)f2bf(v.x) | ((unsigned)f2bf(v.y) << 16);
  o.y = (unsigned)f2bf(v.z) | ((unsigned)f2bf(v.w) << 16);
  return o;
}

__device__ __forceinline__ f32x4 mfma16(bf16x8 a, bf16x8 b, f32x4 c) {
  return __builtin_amdgcn_mfma_f32_16x16x32_bf16(a, b, c, 0, 0, 0);
}

// ============================ router ============================
__global__ __launch_bounds__(256) void router_kernel(
    const float* __restrict__ x, const float* __restrict__ gw,
    float* __restrict__ combine, int* __restrict__ topk_idx) {
  __shared__ float partial[256];
  __shared__ float logits[E_NUM];
  const int t = blockIdx.x, tid = threadIdx.x;
  const int e = tid >> 4, l16 = tid & 15;
  const float* xr = x + (size_t)t * H_DIM;
  const float* wr = gw + (size_t)e * H_DIM;
  float s = 0.f;
  for (int h = l16 * 4; h < H_DIM; h += 64) {
    float4 xv = *(const float4*)&xr[h];
    float4 wv = *(const float4*)&wr[h];
    s += xv.x * wv.x + xv.y * wv.y + xv.z * wv.z + xv.w * wv.w;
  }
  partial[tid] = s;
  __syncthreads();
  if (tid < E_NUM) {
    float tot = 0.f;
    for (int j = 0; j < 16; ++j) tot += partial[tid * 16 + j];
    logits[tid] = tot;
  }
  __syncthreads();
  if (tid == 0) {
    float p[E_NUM];
    float mx = -1e30f;
    for (int i = 0; i < E_NUM; ++i) mx = fmaxf(mx, logits[i]);
    float sum = 0.f;
    for (int i = 0; i < E_NUM; ++i) { p[i] = expf(logits[i] - mx); sum += p[i]; }
    float inv = 1.f / sum;
    for (int i = 0; i < E_NUM; ++i) p[i] *= inv;
    bool used[E_NUM];
    for (int i = 0; i < E_NUM; ++i) used[i] = false;
    int idx[TOPK]; float w4[TOPK]; float wsum = 0.f;
    for (int k = 0; k < TOPK; ++k) {
      int best = 0; float bv = -1.f;
      for (int i = 0; i < E_NUM; ++i)
        if (!used[i] && p[i] > bv) { bv = p[i]; best = i; }
      used[best] = true; idx[k] = best; w4[k] = bv; wsum += bv;
    }
    float outw[E_NUM];
    for (int i = 0; i < E_NUM; ++i) outw[i] = 0.f;
    float winv = 1.f / wsum;
    for (int k = 0; k < TOPK; ++k) {
      outw[idx[k]] = w4[k] * winv;
      topk_idx[t * TOPK + k] = idx[k];
    }
    for (int i = 0; i < E_NUM; ++i) combine[(size_t)t * E_NUM + i] = outw[i];
  }
}

// =================== per-expert gather-list build ===================
__global__ __launch_bounds__(256) void assign_kernel(
    const int* __restrict__ topk_idx, int* __restrict__ list,
    int* __restrict__ cnt, int* __restrict__ cntPad) {
  __shared__ int lcnt[E_NUM], lcur[E_NUM];
  const int tid = threadIdx.x;
  if (tid < E_NUM) { lcnt[tid] = 0; lcur[tid] = 0; }
  __syncthreads();
  for (int t = tid; t < T_TOK; t += 256)
    for (int k = 0; k < TOPK; ++k)
      atomicAdd(&lcnt[topk_idx[t * TOPK + k]], 1);
  __syncthreads();
  for (int t = tid; t < T_TOK; t += 256)
    for (int k = 0; k < TOPK; ++k) {
      int e = topk_idx[t * TOPK + k];
      int p = atomicAdd(&lcur[e], 1);
      list[e * T_TOK + p] = t;
    }
  __syncthreads();
  if (tid < E_NUM) {
    int c = lcnt[tid];
    int cp = (c + 127) / 128 * 128;
    cnt[tid] = c;
    cntPad[tid] = cp;
    int last = (c > 0) ? list[tid * T_TOK + c - 1] : 0;
    for (int p = c; p < cp; ++p) list[tid * T_TOK + p] = last;
  }
}

// =================== fused gate_up + SiLU*mul (routed z<16, shared z>=16) ===
// Tile 128(M) x 64(N), BK=32, 4 waves (2x2, each 64x32).
// acc = 16 f32x4 = 64 AGPR  -> 2-3 waves/SIMD.
// Reg-prefetch of next K-tile issued between the two barriers.
__global__ __launch_bounds__(256, 2) void gateup_kernel(
    const float* __restrict__ X, const float* __restrict__ Wgu,
    const float* __restrict__ Wsh, const float* __restrict__ combine,
    const int* __restrict__ list, const int* __restrict__ cntPad,
    u16* __restrict__ actR, u16* __restrict__ actS) {
  __shared__ u16 As[128 * LDP];
  __shared__ u16 Wg[64 * LDP];
  __shared__ u16 Wu[64 * LDP];
  __shared__ int ltok[128];
  const int z = blockIdx.z;
  const int row0 = blockIdx.y * 128;   // token rows (shared) / positions (routed)
  const int tid = threadIdx.x;
  const int srow = tid >> 3;           // 0..31
  const int scol = (tid & 7) * 4;      // 0,4,..,28

  const float* Arow[4];
  const float* Wgp;
  const float* Wup;
  int n0;
  if (z >= E_NUM) {            // ---- shared expert path ----
    n0 = (blockIdx.x + (z - E_NUM) * 22) * 64;   // 44 n-tiles over IS_DIM
    Wgp = Wsh + (size_t)(n0 + srow) * H_DIM + scol;
    Wup = Wsh + (size_t)(IS_DIM + n0 + srow) * H_DIM + scol;
#pragma unroll
    for (int q = 0; q < 4; ++q)
      Arow[q] = X + (size_t)(row0 + q * 32 + srow) * H_DIM + scol;
  } else {                     // ---- routed expert z ----
    if (row0 >= cntPad[z]) return;
    if (tid < 128) ltok[tid] = list[z * T_TOK + row0 + tid];
    __syncthreads();
    n0 = blockIdx.x * 64;
    Wgp = Wgu + (size_t)z * (2 * I_DIM * H_DIM) + (size_t)(n0 + srow) * H_DIM + scol;
    Wup = Wgp + (size_t)I_DIM * H_DIM;
#pragma unroll
    for (int q = 0; q < 4; ++q)
      Arow[q] = X + (size_t)ltok[q * 32 + srow] * H_DIM + scol;
  }

  const int wave = tid >> 6, lane = tid & 63;
  const int lane16 = lane & 15, quad = lane >> 4;
  const int wm = wave >> 1, wn = wave & 1;

  const f32x4 zero = {0.f, 0.f, 0.f, 0.f};
  f32x4 accg[4][2], accu[4][2];
#pragma unroll
  for (int i = 0; i < 4; ++i)
#pragma unroll
    for (int j = 0; j < 2; ++j) { accg[i][j] = zero; accu[i][j] = zero; }

  float4 pa0, pa1, pa2, pa3, pg0, pg1, pu0, pu1;
#define GU_LOAD(k0)                                 \
  pa0 = *(const float4*)(Arow[0] + (k0));           \
  pa1 = *(const float4*)(Arow[1] + (k0));           \
  pa2 = *(const float4*)(Arow[2] + (k0));           \
  pa3 = *(const float4*)(Arow[3] + (k0));           \
  pg0 = *(const float4*)(Wgp + (k0));               \
  pg1 = *(const float4*)(Wgp + 32 * H_DIM + (k0));  \
  pu0 = *(const float4*)(Wup + (k0));               \
  pu1 = *(const float4*)(Wup + 32 * H_DIM + (k0));

  GU_LOAD(0)
  for (int k0 = 0; k0 < H_DIM; k0 += BK) {
    *(uint2*)&As[srow * LDP + scol]        = cvt4(pa0);
    *(uint2*)&As[(32 + srow) * LDP + scol] = cvt4(pa1);
    *(uint2*)&As[(64 + srow) * LDP + scol] = cvt4(pa2);
    *(uint2*)&As[(96 + srow) * LDP + scol] = cvt4(pa3);
    *(uint2*)&Wg[srow * LDP + scol]        = cvt4(pg0);
    *(uint2*)&Wg[(32 + srow) * LDP + scol] = cvt4(pg1);
    *(uint2*)&Wu[srow * LDP + scol]        = cvt4(pu0);
    *(uint2*)&Wu[(32 + srow) * LDP + scol] = cvt4(pu1);
    __syncthreads();
    if (k0 + BK < H_DIM) { GU_LOAD(k0 + BK) }   // overlap with ds_read+MFMA
    bf16x8 a[4], bg[2], bu[2];
#pragma unroll
    for (int i = 0; i < 4; ++i)
      a[i] = *(const bf16x8*)&As[(wm * 64 + i * 16 + lane16) * LDP + quad * 8];
#pragma unroll
    for (int j = 0; j < 2; ++j) {
      bg[j] = *(const bf16x8*)&Wg[(wn * 32 + j * 16 + lane16) * LDP + quad * 8];
      bu[j] = *(const bf16x8*)&Wu[(wn * 32 + j * 16 + lane16) * LDP + quad * 8];
    }
#pragma unroll
    for (int i = 0; i < 4; ++i)
#pragma unroll
      for (int j = 0; j < 2; ++j) {
        accg[i][j] = mfma16(a[i], bg[j], accg[i][j]);
        accu[i][j] = mfma16(a[i], bu[j], accu[i][j]);
      }
    __syncthreads();
  }
#undef GU_LOAD

  if (z >= E_NUM) {
#pragma unroll
    for (int i = 0; i < 4; ++i)
#pragma unroll
      for (int j = 0; j < 2; ++j) {
        const int col = n0 + wn * 32 + j * 16 + lane16;
#pragma unroll
        for (int r = 0; r < 4; ++r) {
          const int row = row0 + wm * 64 + i * 16 + quad * 4 + r;
          float g = accg[i][j][r], u = accu[i][j][r];
          actS[(size_t)row * IS_DIM + col] = f2bf(g / (1.f + __expf(-g)) * u);
        }
      }
  } else {
#pragma unroll
    for (int i = 0; i < 4; ++i)
#pragma unroll
      for (int j = 0; j < 2; ++j) {
        const int col = n0 + wn * 32 + j * 16 + lane16;
#pragma unroll
        for (int r = 0; r < 4; ++r) {
          const int rl = wm * 64 + i * 16 + quad * 4 + r;
          float g = accg[i][j][r], u = accu[i][j][r];
          float act = g / (1.f + __expf(-g)) * u;
          act *= combine[(size_t)ltok[rl] * E_NUM + z];
          actR[((size_t)z * T_TOK + row0 + rl) * I_DIM + col] = f2bf(act);
        }
      }
  }
}

// =================== fused down-proj (routed z<16, shared z=16) =============
// Tile 128x128, BK=32, 4 waves (2x2, each 64x64). acc = 64 AGPR.
// out is pre-zeroed; BOTH paths atomicAdd (they race within one launch).
// Note: K == row stride for both paths (I_DIM routed, IS_DIM shared).
__global__ __launch_bounds__(256, 2) void down_kernel(
    const u16* __restrict__ actR, const u16* __restrict__ actS,
    const float* __restrict__ Wd, const float* __restrict__ Wsd,
    const int* __restrict__ list, const int* __restrict__ cnt,
    const int* __restrict__ cntPad, float* __restrict__ out) {
  __shared__ u16 As[128 * LDP];
  __shared__ u16 Bs[128 * LDP];
  __shared__ int ltok[128];
  const int z = blockIdx.z;
  const int row0 = blockIdx.y * 128;
  const int col0 = blockIdx.x * 128;
  const int tid = threadIdx.x;
  const int arow = tid >> 2, acol = (tid & 3) * 8;   // A: bf16 128x32
  const int brow = tid >> 3, bcol = (tid & 7) * 4;   // B: fp32 128x32

  int K, c = 0;
  const u16* Ap;
  const float* Bp;
  if (z == E_NUM) {            // ---- shared down ----
    K = IS_DIM;
    Ap = actS + (size_t)(row0 + arow) * IS_DIM + acol;
    Bp = Wsd + (size_t)(col0 + brow) * IS_DIM + bcol;
  } else {                     // ---- routed down ----
    if (row0 >= cntPad[z]) return;
    if (tid < 128) ltok[tid] = list[z * T_TOK + row0 + tid];
    c = cnt[z];
    K = I_DIM;
    Ap = actR + ((size_t)z * T_TOK + row0 + arow) * I_DIM + acol;
    Bp = Wd + ((size_t)z * H_DIM + col0 + brow) * I_DIM + bcol;
  }
  const u16* Ap1 = Ap + (size_t)64 * K;
  const float* Bp1 = Bp + (size_t)32 * K;
  const float* Bp2 = Bp + (size_t)64 * K;
  const float* Bp3 = Bp + (size_t)96 * K;

  const int wave = tid >> 6, lane = tid & 63;
  const int lane16 = lane & 15, quad = lane >> 4;
  const int wm = wave >> 1, wn = wave & 1;

  const f32x4 zero = {0.f, 0.f, 0.f, 0.f};
  f32x4 acc[4][4];
#pragma unroll
  for (int i = 0; i < 4; ++i)
#pragma unroll
    for (int j = 0; j < 4; ++j) acc[i][j] = zero;

  uint4 qa0, qa1; float4 pb0, pb1, pb2, pb3;
#define DN_LOAD(k0)                        \
  qa0 = *(const uint4*)(Ap + (k0));        \
  qa1 = *(const uint4*)(Ap1 + (k0));       \
  pb0 = *(const float4*)(Bp + (k0));       \
  pb1 = *(const float4*)(Bp1 + (k0));      \
  pb2 = *(const float4*)(Bp2 + (k0));      \
  pb3 = *(const float4*)(Bp3 + (k0));

  DN_LOAD(0)
  for (int k0 = 0; k0 < K; k0 += BK) {
    *(uint4*)&As[arow * LDP + acol]        = qa0;
    *(uint4*)&As[(64 + arow) * LDP + acol] = qa1;
    *(uint2*)&Bs[brow * LDP + bcol]        = cvt4(pb0);
    *(uint2*)&Bs[(32 + brow) * LDP + bcol] = cvt4(pb1);
    *(uint2*)&Bs[(64 + brow) * LDP + bcol] = cvt4(pb2);
    *(uint2*)&Bs[(96 + brow) * LDP + bcol] = cvt4(pb3);
    __syncthreads();
    if (k0 + BK < K) { DN_LOAD(k0 + BK) }
    bf16x8 a[4], b[4];
#pragma unroll
    for (int i = 0; i < 4; ++i)
      a[i] = *(const bf16x8*)&As[(wm * 64 + i * 16 + lane16) * LDP + quad * 8];
#pragma unroll
    for (int j = 0; j < 4; ++j)
      b[j] = *(const bf16x8*)&Bs[(wn * 64 + j * 16 + lane16) * LDP + quad * 8];
#pragma unroll
    for (int i = 0; i < 4; ++i)
#pragma unroll
      for (int j = 0; j < 4; ++j) acc[i][j] = mfma16(a[i], b[j], acc[i][j]);
    __syncthreads();
  }
#undef DN_LOAD

  if (z == E_NUM) {
#pragma unroll
    for (int i = 0; i < 4; ++i)
#pragma unroll
      for (int j = 0; j < 4; ++j) {
        const int col = col0 + wn * 64 + j * 16 + lane16;
#pragma unroll
        for (int r = 0; r < 4; ++r) {
          const int row = row0 + wm * 64 + i * 16 + quad * 4 + r;
          atomicAdd(&out[(size_t)row * H_DIM + col], acc[i][j][r]);
        }
      }
  } else {
#pragma unroll
    for (int i = 0; i < 4; ++i)
#pragma unroll
      for (int j = 0; j < 4; ++j) {
        const int col = col0 + wn * 64 + j * 16 + lane16;
#pragma unroll
        for (int r = 0; r < 4; ++r) {
          const int rl = wm * 64 + i * 16 + quad * 4 + r;
          if (row0 + rl < c)
            atomicAdd(&out[(size_t)ltok[rl] * H_DIM + col], acc[i][j][r]);
        }
      }
  }
}

// ============================ launch ============================
extern "C" void kernel_launch(void* const* d_in, const int* in_sizes, int n_in,
                              void* d_out, int out_size, void* d_ws,
                              size_t ws_size, hipStream_t stream) {
  const float* x = (const float*)d_in[0];           // [1024,2048]
  const float* gate_w = (const float*)d_in[1];      // [16,2048]
  const float* w_gate_up = (const float*)d_in[2];   // [16,2816,2048]
  const float* w_down = (const float*)d_in[3];      // [16,2048,1408]
  const float* shared_gu = (const float*)d_in[4];   // [5632,2048]
  const float* shared_down = (const float*)d_in[5]; // [2048,2816]
  float* out = (float*)d_out;

  char* ws = (char*)d_ws;
  float* combine = (float*)ws;                 // 64 KiB fp32 [T,E]
  int* topk_idx = (int*)(ws + 65536);          // 16 KiB [T,4]
  int* list = (int*)(ws + 81920);              // 64 KiB [E,1024]
  int* cnt = (int*)(ws + 147456);              // 64 B
  int* cntPad = (int*)(ws + 147520);           // 64 B
  u16* actS = (u16*)(ws + 147584);             // 5.77 MB bf16 [T,2816]
  u16* actR = (u16*)(ws + 147584 + 5767168);   // 46.1 MB bf16 [E,1024,1408]
  // total ws usage: ~49.6 MiB (unchanged)

  router_kernel<<<T_TOK, 256, 0, stream>>>(x, gate_w, combine, topk_idx);
  assign_kernel<<<1, 256, 0, stream>>>(topk_idx, list, cnt, cntPad);
  hipMemsetAsync(out, 0, (size_t)T_TOK * H_DIM * sizeof(float), stream);

  // z = 0..15 routed experts, z = 16..17 shared expert (44 n-tiles = 2 x 22)
  gateup_kernel<<<dim3(22, 8, 18), 256, 0, stream>>>(
      x, w_gate_up, shared_gu, combine, list, cntPad, actR, actS);

  // z = 0..15 routed down (scatter atomics), z = 16 shared down (atomics)
  down_kernel<<<dim3(16, 8, 17), 256, 0, stream>>>(
      actR, actS, w_down, shared_down, list, cnt, cntPad, out);
}